// Round 14
// baseline (637.482 us; speedup 1.0000x reference)
//
#include <hip/hip_runtime.h>
#include <hip/hip_bf16.h>

typedef __hip_bfloat16 bf16;

__device__ __forceinline__ float b2f(bf16 v) { return __bfloat162float(v); }
__device__ __forceinline__ bf16 f2b(float v) { return __float2bfloat16(v); }
// unpack a dword holding two bf16 (little-endian: low halfword = lower address)
__device__ __forceinline__ void up2(unsigned u, float& lo, float& hi) {
  lo = __uint_as_float(u << 16);
  hi = __uint_as_float(u & 0xFFFF0000u);
}

// Runtime dtype detection (see previous version's rationale).
__device__ __forceinline__ bool detect_f32(const void* p) {
  const unsigned* u = (const unsigned*)p;
  int c = 0;
#pragma unroll
  for (int i = 0; i < 64; ++i) {
    unsigned e = (u[i] >> 7) & 0xFF;
    c += (e >= 170);
  }
  return c > 0;
}

__device__ __forceinline__ float ldp(const void* p, int i, bool f32) {
  return f32 ? ((const float*)p)[i] : b2f(((const bf16*)p)[i]);
}
__device__ __forceinline__ void ldpair(const void* p, size_t du, bool f32,
                                       float& a, float& b) {
  if (f32) {
    float2 v = ((const float2*)p)[du];
    a = v.x; b = v.y;
  } else {
    up2(((const unsigned*)p)[du], a, b);
  }
}
// 4 consecutive params starting at 4-aligned element index i
__device__ __forceinline__ void ld4(const void* p, size_t i, bool f32,
                                    float4& o) {
  if (f32) {
    o = ((const float4*)p)[i >> 2];
  } else {
    uint2 u = ((const uint2*)p)[i >> 2];
    up2(u.x, o.x, o.y);
    up2(u.y, o.z, o.w);
  }
}

#define SCALE 0.17677669529663687f

// ---------------------------------------------------------------------------
// Fused WT + cascaded 8-head windowed attention + relu/proj + IWT.
// v5 (v4 post-mortem: occupancy 22->44% as designed but dur only 441->433
// => occupancy NOT binding; per-block serial phase chain is. WRITE_SIZE
// 427->199MB from denser write timing -- keep 512 threads):
//  - X-REGISTER PREFETCH (v2 retry in fitting regime): at 512 thr the
//    per-thread x slice is 16 regs and VGPR=64, so the prefetch fits
//    (~90 peak < 128 cap; v2 failed at 256 thr because acc[8][8]+32 regs
//    spilled). Next head's x issues at end of S1, consumed 4 barriers later.
//  - DOUBLE-BUFFERED weight LDS (wf/w5/ab x2, +5.4KB -> 68.4KB, still
//    2 blocks/CU): W(h+1) commits during S1(h) interval -> B_a eliminated,
//    4 barriers/head (was 5). Hazards: all readers of buf[cur^1] (head h-1's
//    S1/S2/S3) are fenced behind B_e(h-1) before the commit in S1(h).
//  - from v4: 512 thr/block, shfl softmax, pw direct from global, no
//    trailing barrier after S7.
// ---------------------------------------------------------------------------
__global__ __launch_bounds__(512, 4) void fused_kernel(
    const void* __restrict__ x, const void* __restrict__ wtf,
    const void* __restrict__ iwtf,
    const void* __restrict__ dww, const void* __restrict__ dwb,
    const void* __restrict__ pw, const void* __restrict__ pb,
    const void* __restrict__ ab, const int* __restrict__ bidx,
    void* __restrict__ out) {
  __shared__ float lh_s[32 * 65];
  __shared__ float k_s[32 * 65];
  __shared__ float v_s[32 * 65];
  __shared__ float out_s[32 * 68];
  __shared__ float q_s[64 * 33];
  __shared__ float attn_s[64 * 65];
  __shared__ float w5_s[2][800];
  __shared__ float wf_s[2][512];
  __shared__ float ab_s[2][64];
  __shared__ float inv_s[64];

  const bool xf = detect_f32(x);   // x (and output) dtype
  const bool pf = detect_f32(pw);  // parameter dtype

  int t = threadIdx.x;  // 0..511
  int w = blockIdx.x;   // identity mapping
  int b = w >> 8, wi = w & 255, wy = wi >> 4, wx = wi & 15;

  float acc[4][8] = {};
  int to = t >> 3, tp = t & 7;  // to 0..63, tp 0..7 (S7/epilogue roles)
  int m = t & 63, ng = t >> 6;  // S3 roles: lane m, wave ng (0..7)

  // ---- prologue: commit W(0) to buf0; W(1) + X(0) into regs ----
  {
    wf_s[0][t] = ldp(wtf, t, pf);
#pragma unroll
    for (int e2 = 0; e2 < 2; ++e2) {
      int idx = t + 512 * e2;
      if (idx < 800) w5_s[0][idx] = ldp(dww, idx, pf);
    }
    if (t < 64) ab_s[0][t] = ldp(ab, t, pf);
  }
  float pwf0 = ldp(wtf, 512 + t, pf);
  float pw5r[2];
#pragma unroll
  for (int e2 = 0; e2 < 2; ++e2) {
    int idx = t + 512 * e2;
    pw5r[e2] = (idx < 800) ? ldp(dww, 800 + idx, pf) : 0.f;
  }
  float pabr = (t < 64) ? ldp(ab, 64 + t, pf) : 0.f;

  float X0[4], X1[4], X2[4], X3[4];
#pragma unroll
  for (int e = 0; e < 4; ++e) {
    int idx = t + 512 * e;
    int d = idx >> 6, p = idx & 63, r = p >> 3, cc = p & 7;
    int plane = b * 256 + d;  // head 0
    size_t du = ((size_t)plane << 15) + ((wy * 16 + 2 * r) << 7) + wx * 8 + cc;
    ldpair(x, du, xf, X0[e], X1[e]);
    ldpair(x, du + 128, xf, X2[e], X3[e]);
  }
  __syncthreads();  // prologue barrier: W(0) staged

#pragma unroll 1
  for (int h = 0; h < 8; ++h) {
    const int cur = h & 1;
    // ---- S1: WT from prefetched X regs -> lh / k / v(cascaded) ----
#pragma unroll
    for (int e = 0; e < 4; ++e) {
      int idx = t + 512 * e;
      int d = idx >> 6, p = idx & 63;
      const float* f = wf_s[cur] + d * 16;
      float llv = X0[e] * f[0] + X1[e] * f[1] + X2[e] * f[2] + X3[e] * f[3];
      lh_s[d * 65 + p] = X0[e] * f[4] + X1[e] * f[5] + X2[e] * f[6] + X3[e] * f[7];
      k_s[d * 65 + p] = X0[e] * f[8] + X1[e] * f[9] + X2[e] * f[10] + X3[e] * f[11];
      if (h == 0)
        v_s[d * 65 + p] = llv;
      else
        v_s[d * 65 + p] = out_s[d * 68 + p] + llv;
    }
    // commit W(h+1) regs -> other buffer (readers of it finished at B_e(h-1))
    if (h < 7) {
      wf_s[cur ^ 1][t] = pwf0;
#pragma unroll
      for (int e2 = 0; e2 < 2; ++e2) {
        int idx = t + 512 * e2;
        if (idx < 800) w5_s[cur ^ 1][idx] = pw5r[e2];
      }
      if (t < 64) ab_s[cur ^ 1][t] = pabr;
    }
    // issue W(h+2) loads into regs
    if (h < 6) {
      pwf0 = ldp(wtf, (h + 2) * 512 + t, pf);
#pragma unroll
      for (int e2 = 0; e2 < 2; ++e2) {
        int idx = t + 512 * e2;
        pw5r[e2] = (idx < 800) ? ldp(dww, (h + 2) * 800 + idx, pf) : 0.f;
      }
      if (t < 64) pabr = ldp(ab, (h + 2) * 64 + t, pf);
    }
    // issue X(h+1) loads into regs; they complete during S2..S7
    if (h < 7) {
#pragma unroll
      for (int e = 0; e < 4; ++e) {
        int idx = t + 512 * e;
        int d = idx >> 6, p = idx & 63, r = p >> 3, cc = p & 7;
        int plane = b * 256 + (h + 1) * 32 + d;
        size_t du =
            ((size_t)plane << 15) + ((wy * 16 + 2 * r) << 7) + wx * 8 + cc;
        ldpair(x, du, xf, X0[e], X1[e]);
        ldpair(x, du + 128, xf, X2[e], X3[e]);
      }
    }
    __syncthreads();  // B_b: lh/k/v staged

    // ---- S2: q = zero-padded depthwise 5x5 conv over the 8x8 window ----
    {
      float dwbv = ldp(dwb, h * 32 + (t & 31), pf);  // d == t&31 for all e
#pragma unroll
      for (int e = 0; e < 4; ++e) {
        int idx = t + 512 * e;
        int d = idx & 31, n = idx >> 5;
        int r = n >> 3, cc = n & 7;
        float qa = dwbv;
        for (int u = 0; u < 5; ++u) {
          int rr = r + u - 2;
          if (rr < 0 || rr > 7) continue;
          for (int v = 0; v < 5; ++v) {
            int c2 = cc + v - 2;
            if (c2 < 0 || c2 > 7) continue;
            qa += lh_s[d * 65 + rr * 8 + c2] * w5_s[cur][d * 25 + u * 5 + v];
          }
        }
        q_s[n * 33 + d] = qa;
      }
    }
    __syncthreads();  // B_c: q staged

    // ---- S3 + softmax (fused, in-register): wave ng owns rows ng*8.. ----
    {
      float kreg[32];
#pragma unroll
      for (int d = 0; d < 32; ++d) kreg[d] = k_s[d * 65 + m];
#pragma unroll
      for (int nn = 0; nn < 8; ++nn) {
        int n = ng * 8 + nn;
        float a2 = 0.f;
#pragma unroll
        for (int d = 0; d < 32; ++d) a2 += q_s[n * 33 + d] * kreg[d];
        a2 = a2 * SCALE + ab_s[cur][bidx[n * 64 + m]];
        float mx = a2;
#pragma unroll
        for (int msk = 32; msk > 0; msk >>= 1)
          mx = fmaxf(mx, __shfl_xor(mx, msk, 64));
        float e2 = __expf(a2 - mx);
        float sum = e2;
#pragma unroll
        for (int msk = 32; msk > 0; msk >>= 1) sum += __shfl_xor(sum, msk, 64);
        attn_s[n * 65 + m] = e2;
        if (m == 0) inv_s[n] = 1.f / sum;
      }
    }
    __syncthreads();  // B_d: attn (unnormalized) + inv staged

    // ---- S5: out[d][n] = inv[n] * sum_m v[d][m] attn[n][m] ----
    {
      int d = t & 31, n0 = (t >> 5) * 4;
      float pv[4] = {0, 0, 0, 0};
      for (int mm = 0; mm < 64; ++mm) {
        float vv = v_s[d * 65 + mm];
#pragma unroll
        for (int e = 0; e < 4; ++e) pv[e] += vv * attn_s[(n0 + e) * 65 + mm];
      }
#pragma unroll
      for (int e = 0; e < 4; ++e)
        out_s[d * 68 + n0 + e] = pv[e] * inv_s[n0 + e];
    }
    __syncthreads();  // B_e: out_s published

    // ---- S7: proj accumulate, pw direct from global (L2-resident) ----
    // No trailing barrier: next S1 writes lh/k/v (not read by S7) and reads
    // out_s (S7 also only reads); weight commit targets the other buffer.
#pragma unroll 1
    for (int q4 = 0; q4 < 8; ++q4) {
      float4 w4[4];
#pragma unroll
      for (int i2 = 0; i2 < 4; ++i2)
        ld4(pw, (size_t)(to + 64 * i2) * 256 + h * 32 + q4 * 4, pf, w4[i2]);
#pragma unroll
      for (int j = 0; j < 4; ++j) {
        int kk = q4 * 4 + j;
        float r[8];
#pragma unroll
        for (int pi = 0; pi < 8; ++pi)
          r[pi] = fmaxf(out_s[kk * 68 + tp + 8 * pi], 0.f);
#pragma unroll
        for (int i2 = 0; i2 < 4; ++i2) {
          float wv = (j == 0)   ? w4[i2].x
                     : (j == 1) ? w4[i2].y
                     : (j == 2) ? w4[i2].z
                                : w4[i2].w;
#pragma unroll
          for (int pi = 0; pi < 8; ++pi) acc[i2][pi] += wv * r[pi];
        }
      }
    }
  }

  // ---- Epilogue: +bias, then IWT directly to out (write-only, paired) ----
#pragma unroll 1
  for (int i2 = 0; i2 < 4; ++i2) {
    int o = to + 64 * i2;
    float pbv = ldp(pb, o, pf);
    float f[16], g[16];
#pragma unroll
    for (int e = 0; e < 16; ++e) {
      f[e] = ldp(wtf, o * 16 + e, pf);
      g[e] = ldp(iwtf, o * 16 + e, pf);
    }
    int plane = b * 256 + o;
#pragma unroll
    for (int pi = 0; pi < 8; ++pi) {
      int y = wy * 8 + pi;   // band row
      int xb = wx * 8 + tp;  // band col (== x/out pair-column index)
      float llv = acc[i2][pi] + pbv;
      size_t du = ((size_t)plane << 15) + ((size_t)(2 * y) << 7) + xb;
      float x00, x01, x10, x11;
      ldpair(x, du, xf, x00, x01);
      ldpair(x, du + 128, xf, x10, x11);
      float lhv = x00 * f[4] + x01 * f[5] + x10 * f[6] + x11 * f[7];
      float hlv = x00 * f[8] + x01 * f[9] + x10 * f[10] + x11 * f[11];
      float hhv = x00 * f[12] + x01 * f[13] + x10 * f[14] + x11 * f[15];
#pragma unroll
      for (int sy = 0; sy < 2; ++sy) {
        float v0 = llv * g[0 + sy * 2] + lhv * g[4 + sy * 2] +
                   hlv * g[8 + sy * 2] + hhv * g[12 + sy * 2];
        float v1 = llv * g[1 + sy * 2] + lhv * g[5 + sy * 2] +
                   hlv * g[9 + sy * 2] + hhv * g[13 + sy * 2];
        size_t oi = ((size_t)plane << 15) + ((size_t)(2 * y + sy) << 7) + xb;
        if (xf) {
          ((float2*)out)[oi] = make_float2(v0, v1);
        } else {
          union { bf16 hh2[2]; unsigned u; } pk;
          pk.hh2[0] = f2b(v0);
          pk.hh2[1] = f2b(v1);
          ((unsigned*)out)[oi] = pk.u;
        }
      }
    }
  }
}

extern "C" void kernel_launch(void* const* d_in, const int* in_sizes, int n_in,
                              void* d_out, int out_size, void* d_ws, size_t ws_size,
                              hipStream_t stream) {
  // Expected dict-order element counts:
  // x=33554432, wtf=4096, iwtf=4096, dww=6400, dwb=256, pw=65536, pb=256,
  // ab=512, bidx=4096
  const void *x, *wtf, *iwtf, *dww, *dwb, *pw, *pb, *ab;
  const int* bidx;
  if (in_sizes[0] == 33554432) {  // setup_inputs() dict order
    x = d_in[0]; wtf = d_in[1]; iwtf = d_in[2]; dww = d_in[3]; dwb = d_in[4];
    pw = d_in[5]; pb = d_in[6]; ab = d_in[7]; bidx = (const int*)d_in[8];
  } else if (in_sizes[0] == 512) {  // alphabetical order
    ab = d_in[0]; bidx = (const int*)d_in[1]; dwb = d_in[2]; dww = d_in[3];
    iwtf = d_in[4]; pb = d_in[5]; pw = d_in[6]; wtf = d_in[7]; x = d_in[8];
  } else {  // reversed dict order
    bidx = (const int*)d_in[0]; ab = d_in[1]; pb = d_in[2]; pw = d_in[3];
    dwb = d_in[4]; dww = d_in[5]; iwtf = d_in[6]; wtf = d_in[7]; x = d_in[8];
  }

  fused_kernel<<<512, 512, 0, stream>>>(x, wtf, iwtf, dww, dwb, pw, pb, ab,
                                        bidx, d_out);
}

// Round 15
// 552.529 us; speedup vs baseline: 1.1538x; 1.1538x over previous
//
#include <hip/hip_runtime.h>
#include <hip/hip_bf16.h>

typedef __hip_bfloat16 bf16;

__device__ __forceinline__ float b2f(bf16 v) { return __bfloat162float(v); }
__device__ __forceinline__ bf16 f2b(float v) { return __float2bfloat16(v); }
// unpack a dword holding two bf16 (little-endian: low halfword = lower address)
__device__ __forceinline__ void up2(unsigned u, float& lo, float& hi) {
  lo = __uint_as_float(u << 16);
  hi = __uint_as_float(u & 0xFFFF0000u);
}

// Runtime dtype detection (see previous version's rationale).
__device__ __forceinline__ bool detect_f32(const void* p) {
  const unsigned* u = (const unsigned*)p;
  int c = 0;
#pragma unroll
  for (int i = 0; i < 64; ++i) {
    unsigned e = (u[i] >> 7) & 0xFF;
    c += (e >= 170);
  }
  return c > 0;
}

__device__ __forceinline__ float ldp(const void* p, int i, bool f32) {
  return f32 ? ((const float*)p)[i] : b2f(((const bf16*)p)[i]);
}
__device__ __forceinline__ void ldpair(const void* p, size_t du, bool f32,
                                       float& a, float& b) {
  if (f32) {
    float2 v = ((const float2*)p)[du];
    a = v.x; b = v.y;
  } else {
    up2(((const unsigned*)p)[du], a, b);
  }
}
// 4 consecutive params starting at 4-aligned element index i
__device__ __forceinline__ void ld4(const void* p, size_t i, bool f32,
                                    float4& o) {
  if (f32) {
    o = ((const float4*)p)[i >> 2];
  } else {
    uint2 u = ((const uint2*)p)[i >> 2];
    up2(u.x, o.x, o.y);
    up2(u.y, o.z, o.w);
  }
}

#define SCALE 0.17677669529663687f

// ---------------------------------------------------------------------------
// Fused WT + cascaded 8-head windowed attention + relu/proj + IWT.
// v6 = v5 schedule with __launch_bounds__(512, 2).
// v5 post-mortem: allocator pinned VGPR=64 (empirical rule: budget =
// 512/(2*min_waves_arg); (512,4)->64, (256,2)->128 across v2-v5) and
// SPILLED the ~94-reg live set (kreg32+acc32+Xpre16+weights) -> scratch
// traffic: FETCH +63MB, WRITE +88MB, VALUBusy down, dur 433->484. The v5
// schedule (X-reg prefetch + weight LDS double-buffer, 4 barriers/head)
// was never actually measured unspilled. (512,2) -> budget 128, fits.
// Occupancy unaffected: LDS (68.5KB) caps at 2 blocks/CU = 16 waves, and
// VGPR<=128 sustains 4 waves/EU.
//  - from v5: X-register prefetch (issue in S1, consume next head),
//    double-buffered weight LDS (B_a eliminated, 4 barriers/head).
//  - from v4: 512 thr/block, shfl softmax, pw direct from global, no
//    trailing barrier after S7.
// ---------------------------------------------------------------------------
__global__ __launch_bounds__(512, 2) void fused_kernel(
    const void* __restrict__ x, const void* __restrict__ wtf,
    const void* __restrict__ iwtf,
    const void* __restrict__ dww, const void* __restrict__ dwb,
    const void* __restrict__ pw, const void* __restrict__ pb,
    const void* __restrict__ ab, const int* __restrict__ bidx,
    void* __restrict__ out) {
  __shared__ float lh_s[32 * 65];
  __shared__ float k_s[32 * 65];
  __shared__ float v_s[32 * 65];
  __shared__ float out_s[32 * 68];
  __shared__ float q_s[64 * 33];
  __shared__ float attn_s[64 * 65];
  __shared__ float w5_s[2][800];
  __shared__ float wf_s[2][512];
  __shared__ float ab_s[2][64];
  __shared__ float inv_s[64];

  const bool xf = detect_f32(x);   // x (and output) dtype
  const bool pf = detect_f32(pw);  // parameter dtype

  int t = threadIdx.x;  // 0..511
  int w = blockIdx.x;   // identity mapping
  int b = w >> 8, wi = w & 255, wy = wi >> 4, wx = wi & 15;

  float acc[4][8] = {};
  int to = t >> 3, tp = t & 7;  // to 0..63, tp 0..7 (S7/epilogue roles)
  int m = t & 63, ng = t >> 6;  // S3 roles: lane m, wave ng (0..7)

  // ---- prologue: commit W(0) to buf0; W(1) + X(0) into regs ----
  {
    wf_s[0][t] = ldp(wtf, t, pf);
#pragma unroll
    for (int e2 = 0; e2 < 2; ++e2) {
      int idx = t + 512 * e2;
      if (idx < 800) w5_s[0][idx] = ldp(dww, idx, pf);
    }
    if (t < 64) ab_s[0][t] = ldp(ab, t, pf);
  }
  float pwf0 = ldp(wtf, 512 + t, pf);
  float pw5r[2];
#pragma unroll
  for (int e2 = 0; e2 < 2; ++e2) {
    int idx = t + 512 * e2;
    pw5r[e2] = (idx < 800) ? ldp(dww, 800 + idx, pf) : 0.f;
  }
  float pabr = (t < 64) ? ldp(ab, 64 + t, pf) : 0.f;

  float X0[4], X1[4], X2[4], X3[4];
#pragma unroll
  for (int e = 0; e < 4; ++e) {
    int idx = t + 512 * e;
    int d = idx >> 6, p = idx & 63, r = p >> 3, cc = p & 7;
    int plane = b * 256 + d;  // head 0
    size_t du = ((size_t)plane << 15) + ((wy * 16 + 2 * r) << 7) + wx * 8 + cc;
    ldpair(x, du, xf, X0[e], X1[e]);
    ldpair(x, du + 128, xf, X2[e], X3[e]);
  }
  __syncthreads();  // prologue barrier: W(0) staged

#pragma unroll 1
  for (int h = 0; h < 8; ++h) {
    const int cur = h & 1;
    // ---- S1: WT from prefetched X regs -> lh / k / v(cascaded) ----
#pragma unroll
    for (int e = 0; e < 4; ++e) {
      int idx = t + 512 * e;
      int d = idx >> 6, p = idx & 63;
      const float* f = wf_s[cur] + d * 16;
      float llv = X0[e] * f[0] + X1[e] * f[1] + X2[e] * f[2] + X3[e] * f[3];
      lh_s[d * 65 + p] = X0[e] * f[4] + X1[e] * f[5] + X2[e] * f[6] + X3[e] * f[7];
      k_s[d * 65 + p] = X0[e] * f[8] + X1[e] * f[9] + X2[e] * f[10] + X3[e] * f[11];
      if (h == 0)
        v_s[d * 65 + p] = llv;
      else
        v_s[d * 65 + p] = out_s[d * 68 + p] + llv;
    }
    // commit W(h+1) regs -> other buffer (readers of it finished at B_e(h-1))
    if (h < 7) {
      wf_s[cur ^ 1][t] = pwf0;
#pragma unroll
      for (int e2 = 0; e2 < 2; ++e2) {
        int idx = t + 512 * e2;
        if (idx < 800) w5_s[cur ^ 1][idx] = pw5r[e2];
      }
      if (t < 64) ab_s[cur ^ 1][t] = pabr;
    }
    // issue W(h+2) loads into regs
    if (h < 6) {
      pwf0 = ldp(wtf, (h + 2) * 512 + t, pf);
#pragma unroll
      for (int e2 = 0; e2 < 2; ++e2) {
        int idx = t + 512 * e2;
        pw5r[e2] = (idx < 800) ? ldp(dww, (h + 2) * 800 + idx, pf) : 0.f;
      }
      if (t < 64) pabr = ldp(ab, (h + 2) * 64 + t, pf);
    }
    // issue X(h+1) loads into regs; they complete during S2..S7
    if (h < 7) {
#pragma unroll
      for (int e = 0; e < 4; ++e) {
        int idx = t + 512 * e;
        int d = idx >> 6, p = idx & 63, r = p >> 3, cc = p & 7;
        int plane = b * 256 + (h + 1) * 32 + d;
        size_t du =
            ((size_t)plane << 15) + ((wy * 16 + 2 * r) << 7) + wx * 8 + cc;
        ldpair(x, du, xf, X0[e], X1[e]);
        ldpair(x, du + 128, xf, X2[e], X3[e]);
      }
    }
    __syncthreads();  // B_b: lh/k/v staged

    // ---- S2: q = zero-padded depthwise 5x5 conv over the 8x8 window ----
    {
      float dwbv = ldp(dwb, h * 32 + (t & 31), pf);  // d == t&31 for all e
#pragma unroll
      for (int e = 0; e < 4; ++e) {
        int idx = t + 512 * e;
        int d = idx & 31, n = idx >> 5;
        int r = n >> 3, cc = n & 7;
        float qa = dwbv;
        for (int u = 0; u < 5; ++u) {
          int rr = r + u - 2;
          if (rr < 0 || rr > 7) continue;
          for (int v = 0; v < 5; ++v) {
            int c2 = cc + v - 2;
            if (c2 < 0 || c2 > 7) continue;
            qa += lh_s[d * 65 + rr * 8 + c2] * w5_s[cur][d * 25 + u * 5 + v];
          }
        }
        q_s[n * 33 + d] = qa;
      }
    }
    __syncthreads();  // B_c: q staged

    // ---- S3 + softmax (fused, in-register): wave ng owns rows ng*8.. ----
    {
      float kreg[32];
#pragma unroll
      for (int d = 0; d < 32; ++d) kreg[d] = k_s[d * 65 + m];
#pragma unroll
      for (int nn = 0; nn < 8; ++nn) {
        int n = ng * 8 + nn;
        float a2 = 0.f;
#pragma unroll
        for (int d = 0; d < 32; ++d) a2 += q_s[n * 33 + d] * kreg[d];
        a2 = a2 * SCALE + ab_s[cur][bidx[n * 64 + m]];
        float mx = a2;
#pragma unroll
        for (int msk = 32; msk > 0; msk >>= 1)
          mx = fmaxf(mx, __shfl_xor(mx, msk, 64));
        float e2 = __expf(a2 - mx);
        float sum = e2;
#pragma unroll
        for (int msk = 32; msk > 0; msk >>= 1) sum += __shfl_xor(sum, msk, 64);
        attn_s[n * 65 + m] = e2;
        if (m == 0) inv_s[n] = 1.f / sum;
      }
    }
    __syncthreads();  // B_d: attn (unnormalized) + inv staged

    // ---- S5: out[d][n] = inv[n] * sum_m v[d][m] attn[n][m] ----
    {
      int d = t & 31, n0 = (t >> 5) * 4;
      float pv[4] = {0, 0, 0, 0};
      for (int mm = 0; mm < 64; ++mm) {
        float vv = v_s[d * 65 + mm];
#pragma unroll
        for (int e = 0; e < 4; ++e) pv[e] += vv * attn_s[(n0 + e) * 65 + mm];
      }
#pragma unroll
      for (int e = 0; e < 4; ++e)
        out_s[d * 68 + n0 + e] = pv[e] * inv_s[n0 + e];
    }
    __syncthreads();  // B_e: out_s published

    // ---- S7: proj accumulate, pw direct from global (L2-resident) ----
    // No trailing barrier: next S1 writes lh/k/v (not read by S7) and reads
    // out_s (S7 also only reads); weight commit targets the other buffer.
#pragma unroll 1
    for (int q4 = 0; q4 < 8; ++q4) {
      float4 w4[4];
#pragma unroll
      for (int i2 = 0; i2 < 4; ++i2)
        ld4(pw, (size_t)(to + 64 * i2) * 256 + h * 32 + q4 * 4, pf, w4[i2]);
#pragma unroll
      for (int j = 0; j < 4; ++j) {
        int kk = q4 * 4 + j;
        float r[8];
#pragma unroll
        for (int pi = 0; pi < 8; ++pi)
          r[pi] = fmaxf(out_s[kk * 68 + tp + 8 * pi], 0.f);
#pragma unroll
        for (int i2 = 0; i2 < 4; ++i2) {
          float wv = (j == 0)   ? w4[i2].x
                     : (j == 1) ? w4[i2].y
                     : (j == 2) ? w4[i2].z
                                : w4[i2].w;
#pragma unroll
          for (int pi = 0; pi < 8; ++pi) acc[i2][pi] += wv * r[pi];
        }
      }
    }
  }

  // ---- Epilogue: +bias, then IWT directly to out (write-only, paired) ----
#pragma unroll 1
  for (int i2 = 0; i2 < 4; ++i2) {
    int o = to + 64 * i2;
    float pbv = ldp(pb, o, pf);
    float f[16], g[16];
#pragma unroll
    for (int e = 0; e < 16; ++e) {
      f[e] = ldp(wtf, o * 16 + e, pf);
      g[e] = ldp(iwtf, o * 16 + e, pf);
    }
    int plane = b * 256 + o;
#pragma unroll
    for (int pi = 0; pi < 8; ++pi) {
      int y = wy * 8 + pi;   // band row
      int xb = wx * 8 + tp;  // band col (== x/out pair-column index)
      float llv = acc[i2][pi] + pbv;
      size_t du = ((size_t)plane << 15) + ((size_t)(2 * y) << 7) + xb;
      float x00, x01, x10, x11;
      ldpair(x, du, xf, x00, x01);
      ldpair(x, du + 128, xf, x10, x11);
      float lhv = x00 * f[4] + x01 * f[5] + x10 * f[6] + x11 * f[7];
      float hlv = x00 * f[8] + x01 * f[9] + x10 * f[10] + x11 * f[11];
      float hhv = x00 * f[12] + x01 * f[13] + x10 * f[14] + x11 * f[15];
#pragma unroll
      for (int sy = 0; sy < 2; ++sy) {
        float v0 = llv * g[0 + sy * 2] + lhv * g[4 + sy * 2] +
                   hlv * g[8 + sy * 2] + hhv * g[12 + sy * 2];
        float v1 = llv * g[1 + sy * 2] + lhv * g[5 + sy * 2] +
                   hlv * g[9 + sy * 2] + hhv * g[13 + sy * 2];
        size_t oi = ((size_t)plane << 15) + ((size_t)(2 * y + sy) << 7) + xb;
        if (xf) {
          ((float2*)out)[oi] = make_float2(v0, v1);
        } else {
          union { bf16 hh2[2]; unsigned u; } pk;
          pk.hh2[0] = f2b(v0);
          pk.hh2[1] = f2b(v1);
          ((unsigned*)out)[oi] = pk.u;
        }
      }
    }
  }
}

extern "C" void kernel_launch(void* const* d_in, const int* in_sizes, int n_in,
                              void* d_out, int out_size, void* d_ws, size_t ws_size,
                              hipStream_t stream) {
  // Expected dict-order element counts:
  // x=33554432, wtf=4096, iwtf=4096, dww=6400, dwb=256, pw=65536, pb=256,
  // ab=512, bidx=4096
  const void *x, *wtf, *iwtf, *dww, *dwb, *pw, *pb, *ab;
  const int* bidx;
  if (in_sizes[0] == 33554432) {  // setup_inputs() dict order
    x = d_in[0]; wtf = d_in[1]; iwtf = d_in[2]; dww = d_in[3]; dwb = d_in[4];
    pw = d_in[5]; pb = d_in[6]; ab = d_in[7]; bidx = (const int*)d_in[8];
  } else if (in_sizes[0] == 512) {  // alphabetical order
    ab = d_in[0]; bidx = (const int*)d_in[1]; dwb = d_in[2]; dww = d_in[3];
    iwtf = d_in[4]; pb = d_in[5]; pw = d_in[6]; wtf = d_in[7]; x = d_in[8];
  } else {  // reversed dict order
    bidx = (const int*)d_in[0]; ab = d_in[1]; pb = d_in[2]; pw = d_in[3];
    dwb = d_in[4]; dww = d_in[5]; iwtf = d_in[6]; wtf = d_in[7]; x = d_in[8];
  }

  fused_kernel<<<512, 512, 0, stream>>>(x, wtf, iwtf, dww, dwb, pw, pb, ab,
                                        bidx, d_out);
}

// Round 16
// 547.371 us; speedup vs baseline: 1.1646x; 1.0094x over previous
//
#include <hip/hip_runtime.h>
#include <hip/hip_bf16.h>

typedef __hip_bfloat16 bf16;

__device__ __forceinline__ float b2f(bf16 v) { return __bfloat162float(v); }
__device__ __forceinline__ bf16 f2b(float v) { return __float2bfloat16(v); }
// unpack a dword holding two bf16 (little-endian: low halfword = lower address)
__device__ __forceinline__ void up2(unsigned u, float& lo, float& hi) {
  lo = __uint_as_float(u << 16);
  hi = __uint_as_float(u & 0xFFFF0000u);
}

// Runtime dtype detection (see previous version's rationale).
__device__ __forceinline__ bool detect_f32(const void* p) {
  const unsigned* u = (const unsigned*)p;
  int c = 0;
#pragma unroll
  for (int i = 0; i < 64; ++i) {
    unsigned e = (u[i] >> 7) & 0xFF;
    c += (e >= 170);
  }
  return c > 0;
}

__device__ __forceinline__ float ldp(const void* p, int i, bool f32) {
  return f32 ? ((const float*)p)[i] : b2f(((const bf16*)p)[i]);
}
__device__ __forceinline__ void ldpair(const void* p, size_t du, bool f32,
                                       float& a, float& b) {
  if (f32) {
    float2 v = ((const float2*)p)[du];
    a = v.x; b = v.y;
  } else {
    up2(((const unsigned*)p)[du], a, b);
  }
}
// 4 consecutive params starting at 4-aligned element index i
__device__ __forceinline__ void ld4(const void* p, size_t i, bool f32,
                                    float4& o) {
  if (f32) {
    o = ((const float4*)p)[i >> 2];
  } else {
    uint2 u = ((const uint2*)p)[i >> 2];
    up2(u.x, o.x, o.y);
    up2(u.y, o.z, o.w);
  }
}

#define SCALE 0.17677669529663687f

// ---------------------------------------------------------------------------
// Fused WT + cascaded 8-head windowed attention + relu/proj + IWT.
// v7 (v6 post-mortem: dur 433->400, FETCH 437->265MB (ideal), WRITE
// 199->131MB (ideal), no spill at VGPR=104 -- but Occupancy 44->23%: the
// +5.6KB weight double-buffer pushed LDS to 70144B; 2x70144=140KB exceeds
// the usable LDS pool (~128KB empirically: v4's 2x64512=126KB fit) -> only
// 1 block/CU. The schedule still won despite half the waves.):
//  - SINGLE weight buffer again (LDS back to 64512 -> 2 blocks/CU), but
//    commit W(h+1) AFTER B_d instead of behind a dedicated barrier: last
//    reader of W(h) is S3/ab_s (fenced by B_d); first reader of W(h+1) is
//    S1(h+1) (fenced behind B_e). Commit in the B_d..B_e window is
//    hazard-free with NO extra barrier -> still 4 barriers/head.
//  - from v6: (512,2) launch bounds (VGPR budget 128, no spill at ~104),
//    X-register prefetch (issue in S1, consume next head), 512 thr/block,
//    shfl softmax, pw direct from global, no trailing barrier after S7.
// ---------------------------------------------------------------------------
__global__ __launch_bounds__(512, 2) void fused_kernel(
    const void* __restrict__ x, const void* __restrict__ wtf,
    const void* __restrict__ iwtf,
    const void* __restrict__ dww, const void* __restrict__ dwb,
    const void* __restrict__ pw, const void* __restrict__ pb,
    const void* __restrict__ ab, const int* __restrict__ bidx,
    void* __restrict__ out) {
  __shared__ float lh_s[32 * 65];
  __shared__ float k_s[32 * 65];
  __shared__ float v_s[32 * 65];
  __shared__ float out_s[32 * 68];
  __shared__ float q_s[64 * 33];
  __shared__ float attn_s[64 * 65];
  __shared__ float w5_s[800];
  __shared__ float wf_s[512];
  __shared__ float ab_s[64];
  __shared__ float inv_s[64];

  const bool xf = detect_f32(x);   // x (and output) dtype
  const bool pf = detect_f32(pw);  // parameter dtype

  int t = threadIdx.x;  // 0..511
  int w = blockIdx.x;   // identity mapping
  int b = w >> 8, wi = w & 255, wy = wi >> 4, wx = wi & 15;

  float acc[4][8] = {};
  int to = t >> 3, tp = t & 7;  // to 0..63, tp 0..7 (S7/epilogue roles)
  int m = t & 63, ng = t >> 6;  // S3 roles: lane m, wave ng (0..7)

  // ---- prologue: commit W(0); W(1) + X(0) into regs ----
  {
    wf_s[t] = ldp(wtf, t, pf);
#pragma unroll
    for (int e2 = 0; e2 < 2; ++e2) {
      int idx = t + 512 * e2;
      if (idx < 800) w5_s[idx] = ldp(dww, idx, pf);
    }
    if (t < 64) ab_s[t] = ldp(ab, t, pf);
  }
  float pwf0 = ldp(wtf, 512 + t, pf);
  float pw5r[2];
#pragma unroll
  for (int e2 = 0; e2 < 2; ++e2) {
    int idx = t + 512 * e2;
    pw5r[e2] = (idx < 800) ? ldp(dww, 800 + idx, pf) : 0.f;
  }
  float pabr = (t < 64) ? ldp(ab, 64 + t, pf) : 0.f;

  float X0[4], X1[4], X2[4], X3[4];
#pragma unroll
  for (int e = 0; e < 4; ++e) {
    int idx = t + 512 * e;
    int d = idx >> 6, p = idx & 63, r = p >> 3, cc = p & 7;
    int plane = b * 256 + d;  // head 0
    size_t du = ((size_t)plane << 15) + ((wy * 16 + 2 * r) << 7) + wx * 8 + cc;
    ldpair(x, du, xf, X0[e], X1[e]);
    ldpair(x, du + 128, xf, X2[e], X3[e]);
  }
  __syncthreads();  // prologue barrier: W(0) staged

#pragma unroll 1
  for (int h = 0; h < 8; ++h) {
    // ---- S1: WT from prefetched X regs -> lh / k / v(cascaded) ----
#pragma unroll
    for (int e = 0; e < 4; ++e) {
      int idx = t + 512 * e;
      int d = idx >> 6, p = idx & 63;
      const float* f = wf_s + d * 16;
      float llv = X0[e] * f[0] + X1[e] * f[1] + X2[e] * f[2] + X3[e] * f[3];
      lh_s[d * 65 + p] = X0[e] * f[4] + X1[e] * f[5] + X2[e] * f[6] + X3[e] * f[7];
      k_s[d * 65 + p] = X0[e] * f[8] + X1[e] * f[9] + X2[e] * f[10] + X3[e] * f[11];
      if (h == 0)
        v_s[d * 65 + p] = llv;
      else
        v_s[d * 65 + p] = out_s[d * 68 + p] + llv;
    }
    // issue X(h+1) loads into regs; they complete during S2..S7
    if (h < 7) {
#pragma unroll
      for (int e = 0; e < 4; ++e) {
        int idx = t + 512 * e;
        int d = idx >> 6, p = idx & 63, r = p >> 3, cc = p & 7;
        int plane = b * 256 + (h + 1) * 32 + d;
        size_t du =
            ((size_t)plane << 15) + ((wy * 16 + 2 * r) << 7) + wx * 8 + cc;
        ldpair(x, du, xf, X0[e], X1[e]);
        ldpair(x, du + 128, xf, X2[e], X3[e]);
      }
    }
    __syncthreads();  // B_b: lh/k/v staged

    // ---- S2: q = zero-padded depthwise 5x5 conv over the 8x8 window ----
    {
      float dwbv = ldp(dwb, h * 32 + (t & 31), pf);  // d == t&31 for all e
#pragma unroll
      for (int e = 0; e < 4; ++e) {
        int idx = t + 512 * e;
        int d = idx & 31, n = idx >> 5;
        int r = n >> 3, cc = n & 7;
        float qa = dwbv;
        for (int u = 0; u < 5; ++u) {
          int rr = r + u - 2;
          if (rr < 0 || rr > 7) continue;
          for (int v = 0; v < 5; ++v) {
            int c2 = cc + v - 2;
            if (c2 < 0 || c2 > 7) continue;
            qa += lh_s[d * 65 + rr * 8 + c2] * w5_s[d * 25 + u * 5 + v];
          }
        }
        q_s[n * 33 + d] = qa;
      }
    }
    __syncthreads();  // B_c: q staged

    // ---- S3 + softmax (fused, in-register): wave ng owns rows ng*8.. ----
    {
      float kreg[32];
#pragma unroll
      for (int d = 0; d < 32; ++d) kreg[d] = k_s[d * 65 + m];
#pragma unroll
      for (int nn = 0; nn < 8; ++nn) {
        int n = ng * 8 + nn;
        float a2 = 0.f;
#pragma unroll
        for (int d = 0; d < 32; ++d) a2 += q_s[n * 33 + d] * kreg[d];
        a2 = a2 * SCALE + ab_s[bidx[n * 64 + m]];
        float mx = a2;
#pragma unroll
        for (int msk = 32; msk > 0; msk >>= 1)
          mx = fmaxf(mx, __shfl_xor(mx, msk, 64));
        float e2 = __expf(a2 - mx);
        float sum = e2;
#pragma unroll
        for (int msk = 32; msk > 0; msk >>= 1) sum += __shfl_xor(sum, msk, 64);
        attn_s[n * 65 + m] = e2;
        if (m == 0) inv_s[n] = 1.f / sum;
      }
    }
    __syncthreads();  // B_d: attn (unnormalized) + inv staged; W(h) now dead

    // ---- commit W(h+1) into the (single) weight buffer: hazard-free in
    // the B_d..B_e window (readers of W(h) finished before B_d; readers of
    // W(h+1) start after B_e). Then issue W(h+2) loads.
    if (h < 7) {
      wf_s[t] = pwf0;
#pragma unroll
      for (int e2 = 0; e2 < 2; ++e2) {
        int idx = t + 512 * e2;
        if (idx < 800) w5_s[idx] = pw5r[e2];
      }
      if (t < 64) ab_s[t] = pabr;
    }
    if (h < 6) {
      pwf0 = ldp(wtf, (h + 2) * 512 + t, pf);
#pragma unroll
      for (int e2 = 0; e2 < 2; ++e2) {
        int idx = t + 512 * e2;
        pw5r[e2] = (idx < 800) ? ldp(dww, (h + 2) * 800 + idx, pf) : 0.f;
      }
      if (t < 64) pabr = ldp(ab, (h + 2) * 64 + t, pf);
    }

    // ---- S5: out[d][n] = inv[n] * sum_m v[d][m] attn[n][m] ----
    {
      int d = t & 31, n0 = (t >> 5) * 4;
      float pv[4] = {0, 0, 0, 0};
      for (int mm = 0; mm < 64; ++mm) {
        float vv = v_s[d * 65 + mm];
#pragma unroll
        for (int e = 0; e < 4; ++e) pv[e] += vv * attn_s[(n0 + e) * 65 + mm];
      }
#pragma unroll
      for (int e = 0; e < 4; ++e)
        out_s[d * 68 + n0 + e] = pv[e] * inv_s[n0 + e];
    }
    __syncthreads();  // B_e: out_s published (and W(h+1) commit fenced)

    // ---- S7: proj accumulate, pw direct from global (L2-resident) ----
    // No trailing barrier: next S1 writes lh/k/v (not read by S7) and reads
    // out_s (S7 also only reads) + wf_s (committed before B_e).
#pragma unroll 1
    for (int q4 = 0; q4 < 8; ++q4) {
      float4 w4[4];
#pragma unroll
      for (int i2 = 0; i2 < 4; ++i2)
        ld4(pw, (size_t)(to + 64 * i2) * 256 + h * 32 + q4 * 4, pf, w4[i2]);
#pragma unroll
      for (int j = 0; j < 4; ++j) {
        int kk = q4 * 4 + j;
        float r[8];
#pragma unroll
        for (int pi = 0; pi < 8; ++pi)
          r[pi] = fmaxf(out_s[kk * 68 + tp + 8 * pi], 0.f);
#pragma unroll
        for (int i2 = 0; i2 < 4; ++i2) {
          float wv = (j == 0)   ? w4[i2].x
                     : (j == 1) ? w4[i2].y
                     : (j == 2) ? w4[i2].z
                                : w4[i2].w;
#pragma unroll
          for (int pi = 0; pi < 8; ++pi) acc[i2][pi] += wv * r[pi];
        }
      }
    }
  }

  // ---- Epilogue: +bias, then IWT directly to out (write-only, paired) ----
#pragma unroll 1
  for (int i2 = 0; i2 < 4; ++i2) {
    int o = to + 64 * i2;
    float pbv = ldp(pb, o, pf);
    float f[16], g[16];
#pragma unroll
    for (int e = 0; e < 16; ++e) {
      f[e] = ldp(wtf, o * 16 + e, pf);
      g[e] = ldp(iwtf, o * 16 + e, pf);
    }
    int plane = b * 256 + o;
#pragma unroll
    for (int pi = 0; pi < 8; ++pi) {
      int y = wy * 8 + pi;   // band row
      int xb = wx * 8 + tp;  // band col (== x/out pair-column index)
      float llv = acc[i2][pi] + pbv;
      size_t du = ((size_t)plane << 15) + ((size_t)(2 * y) << 7) + xb;
      float x00, x01, x10, x11;
      ldpair(x, du, xf, x00, x01);
      ldpair(x, du + 128, xf, x10, x11);
      float lhv = x00 * f[4] + x01 * f[5] + x10 * f[6] + x11 * f[7];
      float hlv = x00 * f[8] + x01 * f[9] + x10 * f[10] + x11 * f[11];
      float hhv = x00 * f[12] + x01 * f[13] + x10 * f[14] + x11 * f[15];
#pragma unroll
      for (int sy = 0; sy < 2; ++sy) {
        float v0 = llv * g[0 + sy * 2] + lhv * g[4 + sy * 2] +
                   hlv * g[8 + sy * 2] + hhv * g[12 + sy * 2];
        float v1 = llv * g[1 + sy * 2] + lhv * g[5 + sy * 2] +
                   hlv * g[9 + sy * 2] + hhv * g[13 + sy * 2];
        size_t oi = ((size_t)plane << 15) + ((size_t)(2 * y + sy) << 7) + xb;
        if (xf) {
          ((float2*)out)[oi] = make_float2(v0, v1);
        } else {
          union { bf16 hh2[2]; unsigned u; } pk;
          pk.hh2[0] = f2b(v0);
          pk.hh2[1] = f2b(v1);
          ((unsigned*)out)[oi] = pk.u;
        }
      }
    }
  }
}

extern "C" void kernel_launch(void* const* d_in, const int* in_sizes, int n_in,
                              void* d_out, int out_size, void* d_ws, size_t ws_size,
                              hipStream_t stream) {
  // Expected dict-order element counts:
  // x=33554432, wtf=4096, iwtf=4096, dww=6400, dwb=256, pw=65536, pb=256,
  // ab=512, bidx=4096
  const void *x, *wtf, *iwtf, *dww, *dwb, *pw, *pb, *ab;
  const int* bidx;
  if (in_sizes[0] == 33554432) {  // setup_inputs() dict order
    x = d_in[0]; wtf = d_in[1]; iwtf = d_in[2]; dww = d_in[3]; dwb = d_in[4];
    pw = d_in[5]; pb = d_in[6]; ab = d_in[7]; bidx = (const int*)d_in[8];
  } else if (in_sizes[0] == 512) {  // alphabetical order
    ab = d_in[0]; bidx = (const int*)d_in[1]; dwb = d_in[2]; dww = d_in[3];
    iwtf = d_in[4]; pb = d_in[5]; pw = d_in[6]; wtf = d_in[7]; x = d_in[8];
  } else {  // reversed dict order
    bidx = (const int*)d_in[0]; ab = d_in[1]; pb = d_in[2]; pw = d_in[3];
    dwb = d_in[4]; dww = d_in[5]; iwtf = d_in[6]; wtf = d_in[7]; x = d_in[8];
  }

  fused_kernel<<<512, 512, 0, stream>>>(x, wtf, iwtf, dww, dwb, pw, pb, ab,
                                        bidx, d_out);
}